// Round 2
// baseline (722.245 us; speedup 1.0000x reference)
//
#include <hip/hip_runtime.h>

#define B_    4
#define HIMG  256
#define WIMG  256
#define C_    128
#define NH_   4
#define WS8   8
#define L_    64
#define NWX   32
#define NPATCH (HIMG*WIMG)           // 65536
#define TTOT  (NPATCH + 200)         // 65736
#define SCALE 0.17677669529663689f   // 32^-0.5

typedef __bf16 bf16x8 __attribute__((ext_vector_type(8)));
typedef __bf16 bf16x4 __attribute__((ext_vector_type(4)));
typedef float  f32x4  __attribute__((ext_vector_type(4)));

// ---- shared-memory layout (54272 B total -> 3 blocks/CU) ----
#define SMEM_BYTES 54272
#define SCR_STRIDE 72            // bf16 elems per row (144 B, 16B-multiple)
#define SCR_BYTES  (64*SCR_STRIDE*2)   // 9216 per wave
#define PXS_OFF    (4*SCR_BYTES)       // 36864
#define PX_STRIDE  136                 // bf16 (272 B rows)
// token-block reuse of the same SMEM:
#define TOK_XS_OFF 0                   // [100][136] bf16 (x, later px) = 27200
#define TOK_QS_OFF 27200               // [100][34] bf16 = 6800
#define TOK_KS_OFF 34000
#define TOK_VS_OFF 40800               // end 47600
#define TOK_STR    34

// ---- workspace layout (bytes) ----
#define WS_WQ     0          // 384*128 bf16 = 98304
#define WS_WP     98304      // 128*128 bf16 = 32768
#define WS_BIAS   131072     // 4*64*64 f32  = 65536
#define WS_QKVTOK 196608     // 8 * 38400 f32 = 1228800  (qkv^T per (b,set))

// ---------------------------------------------------------------- prep
__global__ __launch_bounds__(256)
void prep_kernel(const float* __restrict__ Wq, const float* __restrict__ Wp,
                 const float* __restrict__ rel_table, const int* __restrict__ rel_index,
                 unsigned short* __restrict__ wq_b, unsigned short* __restrict__ wp_b,
                 float* __restrict__ biasT) {
    int id = blockIdx.x * 256 + threadIdx.x;
    if (id < 49152) {
        __bf16 v = (__bf16)Wq[id];
        wq_b[id] = *(unsigned short*)&v;
    } else if (id < 65536) {
        int i = id - 49152;
        __bf16 v = (__bf16)Wp[i];
        wp_b[i] = *(unsigned short*)&v;
    } else if (id < 81920) {
        int t = id - 65536;
        int h = t >> 12, ij = t & 4095;
        biasT[h * 4096 + ij] = rel_table[rel_index[ij] * 4 + h];
    }
}

// ---------------------------------------------------------------- fused kernel
// blocks 0..7: token path (b,set).  blocks 8..4103: window path.
__global__ __launch_bounds__(256, 3)
void fused_kernel(const float* __restrict__ x, const float* __restrict__ det,
                  const float* __restrict__ inter, const float* __restrict__ mask,
                  const unsigned short* __restrict__ wq_u, const float* __restrict__ bqkv,
                  const unsigned short* __restrict__ wp_u, const float* __restrict__ bproj,
                  const float* __restrict__ biasT, float* __restrict__ qkvT_ws,
                  float* __restrict__ out) {
    __shared__ __align__(16) char SMEM[SMEM_BYTES];
    const __bf16* wq = (const __bf16*)wq_u;
    const __bf16* wp = (const __bf16*)wp_u;
    const int tid = threadIdx.x;
    const int bx = blockIdx.x;
    const f32x4 zz = {0.f, 0.f, 0.f, 0.f};

    if (bx >= 8) {
        // ================= window path =================
        const int wbx = bx - 8;
        const int w  = tid >> 6;          // wave == head
        const int l  = tid & 63;
        const int lo = l & 15;
        const int hi = l >> 4;
        const int b  = wbx >> 10;
        const int wi = (wbx >> 5) & 31;
        const int wj = wbx & 31;

        __bf16* SW  = (__bf16*)(SMEM + w * SCR_BYTES);   // per-wave scratch [64][72]
        __bf16* PXS = (__bf16*)(SMEM + PXS_OFF);         // shared px [64][136]

        // ---------------- phase 1: QKV accumulators
        const float* xw = x + (((size_t)(b * HIMG) + wi * WS8) * WIMG + wj * WS8) * C_;
        const float* arow[4];
#pragma unroll
        for (int mt = 0; mt < 4; ++mt) {
            int t = mt * 16 + lo;
            arow[mt] = xw + ((size_t)(t >> 3) * WIMG + (t & 7)) * C_ + hi * 8;
        }
        int nbase[6];
        const __bf16* brow[6];
#pragma unroll
        for (int g = 0; g < 3; ++g) {
            nbase[2 * g]     = g * 128 + 32 * w;
            nbase[2 * g + 1] = g * 128 + 32 * w + 16;
        }
#pragma unroll
        for (int nt = 0; nt < 6; ++nt)
            brow[nt] = wq + (size_t)(nbase[nt] + lo) * C_ + hi * 8;

        f32x4 acc[4][6];
#pragma unroll
        for (int mt = 0; mt < 4; ++mt)
#pragma unroll
            for (int nt = 0; nt < 6; ++nt) acc[mt][nt] = zz;

#pragma unroll
        for (int ks = 0; ks < 4; ++ks) {
            bf16x8 a[4], bb[6];
#pragma unroll
            for (int mt = 0; mt < 4; ++mt) {
                const float* pa = arow[mt] + ks * 32;
                float4 v0 = *(const float4*)pa;
                float4 v1 = *(const float4*)(pa + 4);
                bf16x8 av;
                av[0] = (__bf16)v0.x; av[1] = (__bf16)v0.y; av[2] = (__bf16)v0.z; av[3] = (__bf16)v0.w;
                av[4] = (__bf16)v1.x; av[5] = (__bf16)v1.y; av[6] = (__bf16)v1.z; av[7] = (__bf16)v1.w;
                a[mt] = av;
            }
#pragma unroll
            for (int nt = 0; nt < 6; ++nt)
                bb[nt] = *(const bf16x8*)(brow[nt] + ks * 32);
#pragma unroll
            for (int mt = 0; mt < 4; ++mt)
#pragma unroll
                for (int nt = 0; nt < 6; ++nt)
                    acc[mt][nt] = __builtin_amdgcn_mfma_f32_16x16x32_bf16(a[mt], bb[nt], acc[mt][nt], 0, 0, 0);
        }

        // ---------------- Q through scratch (cols 0..31 local)
#pragma unroll
        for (int nt = 0; nt < 2; ++nt) {
            float bq = bqkv[nbase[nt] + lo];
            int col = nt * 16 + lo;
#pragma unroll
            for (int mt = 0; mt < 4; ++mt)
#pragma unroll
                for (int r = 0; r < 4; ++r)
                    SW[(mt * 16 + hi * 4 + r) * SCR_STRIDE + col] = (__bf16)(acc[mt][nt][r] + bq);
        }
        bf16x8 aq[4];
#pragma unroll
        for (int mt = 0; mt < 4; ++mt)
            aq[mt] = *(const bf16x8*)&SW[(mt * 16 + lo) * SCR_STRIDE + hi * 8];

        // ---------------- K through scratch
#pragma unroll
        for (int nt = 2; nt < 4; ++nt) {
            float bq = bqkv[nbase[nt] + lo];
            int col = (nt - 2) * 16 + lo;
#pragma unroll
            for (int mt = 0; mt < 4; ++mt)
#pragma unroll
                for (int r = 0; r < 4; ++r)
                    SW[(mt * 16 + hi * 4 + r) * SCR_STRIDE + col] = (__bf16)(acc[mt][nt][r] + bq);
        }
        bf16x8 bk[4];
#pragma unroll
        for (int nt = 0; nt < 4; ++nt)
            bk[nt] = *(const bf16x8*)&SW[(nt * 16 + lo) * SCR_STRIDE + hi * 8];

        // ---------------- V^T through scratch: SW[d][tok], d in 0..31
#pragma unroll
        for (int nt = 4; nt < 6; ++nt) {
            float bq = bqkv[nbase[nt] + lo];
            int d = (nt - 4) * 16 + lo;
#pragma unroll
            for (int mt = 0; mt < 4; ++mt) {
                bf16x4 vv;
#pragma unroll
                for (int r = 0; r < 4; ++r) vv[r] = (__bf16)(acc[mt][nt][r] + bq);
                *(bf16x4*)&SW[d * SCR_STRIDE + mt * 16 + hi * 4] = vv;
            }
        }
        bf16x8 bv[2][2];
#pragma unroll
        for (int ks = 0; ks < 2; ++ks)
#pragma unroll
            for (int nt = 0; nt < 2; ++nt)
                bv[ks][nt] = *(const bf16x8*)&SW[(nt * 16 + lo) * SCR_STRIDE + ks * 32 + hi * 8];

        // ---------------- QK^T
        f32x4 lg[4][4];
#pragma unroll
        for (int mt = 0; mt < 4; ++mt)
#pragma unroll
            for (int nt = 0; nt < 4; ++nt)
                lg[mt][nt] = __builtin_amdgcn_mfma_f32_16x16x32_bf16(aq[mt], bk[nt], zz, 0, 0, 0);

        // ---------------- softmax, P -> scratch
        const float* biasH = biasT + w * 4096;
        const float* maskW = mask + (size_t)(wi * NWX + wj) * 4096;
#pragma unroll
        for (int mt = 0; mt < 4; ++mt) {
#pragma unroll
            for (int r = 0; r < 4; ++r) {
                int row = mt * 16 + hi * 4 + r;
                float v[4];
                float m = -1e30f;
#pragma unroll
                for (int nt = 0; nt < 4; ++nt) {
                    int col = nt * 16 + lo;
                    float t = lg[mt][nt][r] * SCALE + biasH[row * 64 + col] + maskW[row * 64 + col];
                    v[nt] = t;
                    m = fmaxf(m, t);
                }
                m = fmaxf(m, __shfl_xor(m, 1));
                m = fmaxf(m, __shfl_xor(m, 2));
                m = fmaxf(m, __shfl_xor(m, 4));
                m = fmaxf(m, __shfl_xor(m, 8));
                float s = 0.f;
#pragma unroll
                for (int nt = 0; nt < 4; ++nt) { v[nt] = __expf(v[nt] - m); s += v[nt]; }
                s += __shfl_xor(s, 1);
                s += __shfl_xor(s, 2);
                s += __shfl_xor(s, 4);
                s += __shfl_xor(s, 8);
                float inv = 1.0f / s;
#pragma unroll
                for (int nt = 0; nt < 4; ++nt)
                    SW[row * SCR_STRIDE + nt * 16 + lo] = (__bf16)(v[nt] * inv);
            }
        }

        // ---------------- PV
        f32x4 pv[4][2];
#pragma unroll
        for (int mt = 0; mt < 4; ++mt)
#pragma unroll
            for (int nt = 0; nt < 2; ++nt) pv[mt][nt] = zz;
#pragma unroll
        for (int ks = 0; ks < 2; ++ks) {
            bf16x8 ap[4];
#pragma unroll
            for (int mt = 0; mt < 4; ++mt)
                ap[mt] = *(const bf16x8*)&SW[(mt * 16 + lo) * SCR_STRIDE + ks * 32 + hi * 8];
#pragma unroll
            for (int mt = 0; mt < 4; ++mt)
#pragma unroll
                for (int nt = 0; nt < 2; ++nt)
                    pv[mt][nt] = __builtin_amdgcn_mfma_f32_16x16x32_bf16(ap[mt], bv[ks][nt], pv[mt][nt], 0, 0, 0);
        }
        // px -> shared PXS (own cols 32w..32w+31)
#pragma unroll
        for (int mt = 0; mt < 4; ++mt)
#pragma unroll
            for (int nt = 0; nt < 2; ++nt)
#pragma unroll
                for (int r = 0; r < 4; ++r)
                    PXS[(mt * 16 + hi * 4 + r) * PX_STRIDE + 32 * w + nt * 16 + lo] = (__bf16)pv[mt][nt][r];

        __syncthreads();

        // ---------------- proj (wave w -> out cols [32w, 32w+32))
        f32x4 po[4][2];
#pragma unroll
        for (int mt = 0; mt < 4; ++mt)
#pragma unroll
            for (int nt = 0; nt < 2; ++nt) po[mt][nt] = zz;
        const __bf16* wprow[2];
#pragma unroll
        for (int nt = 0; nt < 2; ++nt)
            wprow[nt] = wp + (size_t)(32 * w + nt * 16 + lo) * C_ + hi * 8;
#pragma unroll
        for (int ks = 0; ks < 4; ++ks) {
            bf16x8 apx[4], bw[2];
#pragma unroll
            for (int mt = 0; mt < 4; ++mt)
                apx[mt] = *(const bf16x8*)&PXS[(mt * 16 + lo) * PX_STRIDE + ks * 32 + hi * 8];
#pragma unroll
            for (int nt = 0; nt < 2; ++nt)
                bw[nt] = *(const bf16x8*)(wprow[nt] + ks * 32);
#pragma unroll
            for (int mt = 0; mt < 4; ++mt)
#pragma unroll
                for (int nt = 0; nt < 2; ++nt)
                    po[mt][nt] = __builtin_amdgcn_mfma_f32_16x16x32_bf16(apx[mt], bw[nt], po[mt][nt], 0, 0, 0);
        }
        float bp0 = bproj[32 * w + lo];
        float bp1 = bproj[32 * w + 16 + lo];
        float* outb = out + (size_t)b * TTOT * C_;
#pragma unroll
        for (int mt = 0; mt < 4; ++mt) {
#pragma unroll
            for (int r = 0; r < 4; ++r) {
                int row = mt * 16 + hi * 4 + r;
                int tok = (wi * 8 + (row >> 3)) * WIMG + wj * 8 + (row & 7);
                float* orow = outb + (size_t)tok * C_ + 32 * w + lo;
                orow[0]  = po[mt][0][r] + bp0;
                orow[16] = po[mt][1][r] + bp1;
            }
        }
    } else {
        // ================= token path: one block per (b,set) =================
        const int tb  = bx;
        const int b   = tb >> 1;
        const int set = tb & 1;
        const float* src = set ? (inter + (size_t)b * 100 * C_) : (det + (size_t)b * 100 * C_);
        __bf16* xs = (__bf16*)(SMEM + TOK_XS_OFF);   // [100][136]: x, later px
        __bf16* qs = (__bf16*)(SMEM + TOK_QS_OFF);   // [100][34]
        __bf16* ks2 = (__bf16*)(SMEM + TOK_KS_OFF);
        __bf16* vs2 = (__bf16*)(SMEM + TOK_VS_OFF);
        float* qkvT = qkvT_ws + (size_t)tb * 38400;

        // load x -> bf16 LDS
        for (int i = tid; i < 12800; i += 256) {
            int t = i >> 7, c = i & 127;
            xs[t * PX_STRIDE + c] = (__bf16)src[i];
        }
        __syncthreads();

        // qkv: qkvT[n*100+t] = x[t]·Wq[n] + b[n]   (n-major -> coalesced writes, Wq broadcast)
        for (int idx = tid; idx < 38400; idx += 256) {
            int n = idx / 100;
            int t = idx - n * 100;
            float s = 0.f;
#pragma unroll
            for (int k = 0; k < 128; k += 8) {
                bf16x8 xv = *(const bf16x8*)&xs[t * PX_STRIDE + k];
                bf16x8 wv = *(const bf16x8*)&wq[n * C_ + k];
#pragma unroll
                for (int u = 0; u < 8; ++u) s += (float)xv[u] * (float)wv[u];
            }
            qkvT[idx] = s + bqkv[n];
        }
        __syncthreads();

        // attention per head
        for (int h = 0; h < 4; ++h) {
            for (int i = tid; i < 3200; i += 256) {
                int nl = i / 100;
                int t = i - nl * 100;
                qs[t * TOK_STR + nl]  = (__bf16)qkvT[(32 * h + nl) * 100 + t];
                ks2[t * TOK_STR + nl] = (__bf16)qkvT[(128 + 32 * h + nl) * 100 + t];
                vs2[t * TOK_STR + nl] = (__bf16)qkvT[(256 + 32 * h + nl) * 100 + t];
            }
            __syncthreads();
            if (tid < 100) {
                int t = tid;
                float qreg[32];
#pragma unroll
                for (int d = 0; d < 32; ++d) qreg[d] = (float)qs[t * TOK_STR + d];
                float m = -1e30f;
                for (int j = 0; j < 100; ++j) {
                    float s = 0.f;
#pragma unroll
                    for (int d = 0; d < 32; ++d) s += qreg[d] * (float)ks2[j * TOK_STR + d];
                    m = fmaxf(m, s * SCALE);
                }
                float sum = 0.f;
                float acc32[32];
#pragma unroll
                for (int d = 0; d < 32; ++d) acc32[d] = 0.f;
                for (int j = 0; j < 100; ++j) {
                    float s = 0.f;
#pragma unroll
                    for (int d = 0; d < 32; ++d) s += qreg[d] * (float)ks2[j * TOK_STR + d];
                    float p = __expf(s * SCALE - m);
                    sum += p;
#pragma unroll
                    for (int d = 0; d < 32; ++d) acc32[d] += p * (float)vs2[j * TOK_STR + d];
                }
                float inv = 1.0f / sum;
#pragma unroll
                for (int d = 0; d < 32; ++d)
                    xs[t * PX_STRIDE + 32 * h + d] = (__bf16)(acc32[d] * inv);
            }
            __syncthreads();
        }

        // proj: out[t][c] = px[t]·Wp[c] + bp[c]
        for (int idx = tid; idx < 12800; idx += 256) {
            int t = idx >> 7, c = idx & 127;
            float s = 0.f;
#pragma unroll
            for (int k = 0; k < 128; k += 8) {
                bf16x8 a = *(const bf16x8*)&xs[t * PX_STRIDE + k];
                bf16x8 bwv = *(const bf16x8*)&wp[c * C_ + k];
#pragma unroll
                for (int u = 0; u < 8; ++u) s += (float)a[u] * (float)bwv[u];
            }
            out[((size_t)b * TTOT + NPATCH + set * 100 + t) * C_ + c] = s + bproj[c];
        }
    }
}

// ---------------------------------------------------------------- launch
extern "C" void kernel_launch(void* const* d_in, const int* in_sizes, int n_in,
                              void* d_out, int out_size, void* d_ws, size_t ws_size,
                              hipStream_t stream) {
    const float* x         = (const float*)d_in[0];
    const float* det       = (const float*)d_in[1];
    const float* inter     = (const float*)d_in[2];
    const float* mask      = (const float*)d_in[3];
    const float* Wq        = (const float*)d_in[4];
    const float* bq        = (const float*)d_in[5];
    const float* Wp        = (const float*)d_in[6];
    const float* bp        = (const float*)d_in[7];
    const float* rel_table = (const float*)d_in[8];
    const int*   rel_index = (const int*)d_in[9];
    float* out = (float*)d_out;

    char* ws = (char*)d_ws;
    unsigned short* wq_b = (unsigned short*)(ws + WS_WQ);
    unsigned short* wp_b = (unsigned short*)(ws + WS_WP);
    float* biasT         = (float*)(ws + WS_BIAS);
    float* qkvT_ws       = (float*)(ws + WS_QKVTOK);

    prep_kernel<<<320, 256, 0, stream>>>(Wq, Wp, rel_table, rel_index, wq_b, wp_b, biasT);
    fused_kernel<<<4104, 256, 0, stream>>>(x, det, inter, mask, wq_b, bq, wp_b, bp,
                                           biasT, qkvT_ws, out);
}

// Round 3
// 704.435 us; speedup vs baseline: 1.0253x; 1.0253x over previous
//
#include <hip/hip_runtime.h>

#define B_    4
#define HIMG  256
#define WIMG  256
#define C_    128
#define NH_   4
#define WS8   8
#define L_    64
#define NWX   32
#define NPATCH (HIMG*WIMG)           // 65536
#define TTOT  (NPATCH + 200)         // 65736
#define SCALE 0.17677669529663689f   // 32^-0.5

typedef __bf16 bf16x8 __attribute__((ext_vector_type(8)));
typedef __bf16 bf16x4 __attribute__((ext_vector_type(4)));
typedef float  f32x4  __attribute__((ext_vector_type(4)));

// ---- shared-memory layout (72704 B total -> 2 blocks/CU, reg cap 256) ----
#define SMEM_BYTES 72704
#define WV_STRIDE  72                // bf16 elems per scratch row (144 B)
#define KOFF       40                // K cols 40..71 (byte 80: 16B-aligned)
#define QKP_BYTES  (64*WV_STRIDE*2)  // 9216: Q+K, later P
#define VT_OFF     QKP_BYTES         // per-wave VT [32][72] = 4608 B
#define WV_BYTES   (QKP_BYTES + 32*WV_STRIDE*2)   // 13824 per wave
#define PXS_OFF    (4*WV_BYTES)      // 55296: shared px [64][136] = 17408 B
#define PX_STRIDE  136
// token-block reuse of the same SMEM (47600 B used):
#define TOK_XS_OFF 0
#define TOK_QS_OFF 27200
#define TOK_KS_OFF 34000
#define TOK_VS_OFF 40800
#define TOK_STR    34

// ---- workspace layout (bytes) ----
#define WS_WQ     0          // 384*128 bf16 = 98304
#define WS_WP     98304      // 128*128 bf16 = 32768
#define WS_BIAS   131072     // 4*64*64 f32  = 65536
#define WS_QKVTOK 196608     // 8 * 38400 f32 = 1228800

// ---------------------------------------------------------------- prep
__global__ __launch_bounds__(256)
void prep_kernel(const float* __restrict__ Wq, const float* __restrict__ Wp,
                 const float* __restrict__ rel_table, const int* __restrict__ rel_index,
                 unsigned short* __restrict__ wq_b, unsigned short* __restrict__ wp_b,
                 float* __restrict__ biasT) {
    int id = blockIdx.x * 256 + threadIdx.x;
    if (id < 49152) {
        __bf16 v = (__bf16)Wq[id];
        wq_b[id] = *(unsigned short*)&v;
    } else if (id < 65536) {
        int i = id - 49152;
        __bf16 v = (__bf16)Wp[i];
        wp_b[i] = *(unsigned short*)&v;
    } else if (id < 81920) {
        int t = id - 65536;
        int h = t >> 12, ij = t & 4095;
        biasT[h * 4096 + ij] = rel_table[rel_index[ij] * 4 + h];
    }
}

// ---------------------------------------------------------------- fused kernel
// blocks 0..7: token path (b,set).  blocks 8..4103: window path (XCD-grouped).
__global__ __launch_bounds__(256, 2)
void fused_kernel(const float* __restrict__ x, const float* __restrict__ det,
                  const float* __restrict__ inter, const float* __restrict__ mask,
                  const unsigned short* __restrict__ wq_u, const float* __restrict__ bqkv,
                  const unsigned short* __restrict__ wp_u, const float* __restrict__ bproj,
                  const float* __restrict__ biasT, float* __restrict__ qkvT_ws,
                  float* __restrict__ out) {
    __shared__ __align__(16) char SMEM[SMEM_BYTES];
    const __bf16* wq = (const __bf16*)wq_u;
    const __bf16* wp = (const __bf16*)wp_u;
    const int tid = threadIdx.x;
    const int bx = blockIdx.x;
    const f32x4 zz = {0.f, 0.f, 0.f, 0.f};

    if (bx >= 8) {
        // ================= window path =================
        // XCD-bijective remap: 4 batch-copies of one window -> same XCD (bx%8),
        // adjacent in dispatch -> 16KB mask slice stays L2-hot.
        const int wbx = bx - 8;
        const int xcd = wbx & 7;
        const int grp = wbx >> 3;
        const int b   = grp & 3;
        const int widx = xcd + 8 * (grp >> 2);   // 0..1023
        const int wi = widx >> 5;
        const int wj = widx & 31;

        const int w  = tid >> 6;          // wave == head
        const int l  = tid & 63;
        const int lo = l & 15;
        const int hi = l >> 4;

        __bf16* SW  = (__bf16*)(SMEM + w * WV_BYTES);            // [64][72]: Q|K, later P
        __bf16* VTs = (__bf16*)(SMEM + w * WV_BYTES + VT_OFF);   // [32][72]: V^T
        __bf16* PXS = (__bf16*)(SMEM + PXS_OFF);                 // [64][136]: px

        // ---------------- phase 1: QKV accumulators
        const float* xw = x + (((size_t)(b * HIMG) + wi * WS8) * WIMG + wj * WS8) * C_;
        const float* arow[4];
#pragma unroll
        for (int mt = 0; mt < 4; ++mt) {
            int t = mt * 16 + lo;
            arow[mt] = xw + ((size_t)(t >> 3) * WIMG + (t & 7)) * C_ + hi * 8;
        }
        int nbase[6];
        const __bf16* brow[6];
#pragma unroll
        for (int g = 0; g < 3; ++g) {
            nbase[2 * g]     = g * 128 + 32 * w;
            nbase[2 * g + 1] = g * 128 + 32 * w + 16;
        }
#pragma unroll
        for (int nt = 0; nt < 6; ++nt)
            brow[nt] = wq + (size_t)(nbase[nt] + lo) * C_ + hi * 8;

        f32x4 acc[4][6];
#pragma unroll
        for (int mt = 0; mt < 4; ++mt)
#pragma unroll
            for (int nt = 0; nt < 6; ++nt) acc[mt][nt] = zz;

#pragma unroll
        for (int ks = 0; ks < 4; ++ks) {
            bf16x8 a[4], bb[6];
#pragma unroll
            for (int mt = 0; mt < 4; ++mt) {
                const float* pa = arow[mt] + ks * 32;
                float4 v0 = *(const float4*)pa;
                float4 v1 = *(const float4*)(pa + 4);
                bf16x8 av;
                av[0] = (__bf16)v0.x; av[1] = (__bf16)v0.y; av[2] = (__bf16)v0.z; av[3] = (__bf16)v0.w;
                av[4] = (__bf16)v1.x; av[5] = (__bf16)v1.y; av[6] = (__bf16)v1.z; av[7] = (__bf16)v1.w;
                a[mt] = av;
            }
#pragma unroll
            for (int nt = 0; nt < 6; ++nt)
                bb[nt] = *(const bf16x8*)(brow[nt] + ks * 32);
#pragma unroll
            for (int mt = 0; mt < 4; ++mt)
#pragma unroll
                for (int nt = 0; nt < 6; ++nt)
                    acc[mt][nt] = __builtin_amdgcn_mfma_f32_16x16x32_bf16(a[mt], bb[nt], acc[mt][nt], 0, 0, 0);
        }

        // ---------------- scatter Q, K, V^T to LDS (write all, then read: 1 wait)
#pragma unroll
        for (int nt = 0; nt < 6; ++nt) {
            float bq = bqkv[nbase[nt] + lo];
            if (nt < 2) {
                int col = nt * 16 + lo;
#pragma unroll
                for (int mt = 0; mt < 4; ++mt)
#pragma unroll
                    for (int r = 0; r < 4; ++r)
                        SW[(mt * 16 + hi * 4 + r) * WV_STRIDE + col] = (__bf16)(acc[mt][nt][r] + bq);
            } else if (nt < 4) {
                int col = KOFF + (nt - 2) * 16 + lo;
#pragma unroll
                for (int mt = 0; mt < 4; ++mt)
#pragma unroll
                    for (int r = 0; r < 4; ++r)
                        SW[(mt * 16 + hi * 4 + r) * WV_STRIDE + col] = (__bf16)(acc[mt][nt][r] + bq);
            } else {
                int d = (nt - 4) * 16 + lo;
#pragma unroll
                for (int mt = 0; mt < 4; ++mt) {
                    bf16x4 vv;
#pragma unroll
                    for (int r = 0; r < 4; ++r) vv[r] = (__bf16)(acc[mt][nt][r] + bq);
                    *(bf16x4*)&VTs[d * WV_STRIDE + mt * 16 + hi * 4] = vv;
                }
            }
        }

        bf16x8 aq[4], bk[4];
#pragma unroll
        for (int mt = 0; mt < 4; ++mt)
            aq[mt] = *(const bf16x8*)&SW[(mt * 16 + lo) * WV_STRIDE + hi * 8];
#pragma unroll
        for (int nt = 0; nt < 4; ++nt)
            bk[nt] = *(const bf16x8*)&SW[(nt * 16 + lo) * WV_STRIDE + KOFF + hi * 8];

        // ---------------- QK^T
        f32x4 lg[4][4];
#pragma unroll
        for (int mt = 0; mt < 4; ++mt)
#pragma unroll
            for (int nt = 0; nt < 4; ++nt)
                lg[mt][nt] = __builtin_amdgcn_mfma_f32_16x16x32_bf16(aq[mt], bk[nt], zz, 0, 0, 0);

        // ---------------- softmax, P -> scratch (reuses Q/K region; Q/K already in regs)
        const float* biasH = biasT + w * 4096;
        const float* maskW = mask + (size_t)(wi * NWX + wj) * 4096;
#pragma unroll
        for (int mt = 0; mt < 4; ++mt) {
#pragma unroll
            for (int r = 0; r < 4; ++r) {
                int row = mt * 16 + hi * 4 + r;
                float v[4];
                float m = -1e30f;
#pragma unroll
                for (int nt = 0; nt < 4; ++nt) {
                    int col = nt * 16 + lo;
                    float t = lg[mt][nt][r] * SCALE + biasH[row * 64 + col] + maskW[row * 64 + col];
                    v[nt] = t;
                    m = fmaxf(m, t);
                }
                m = fmaxf(m, __shfl_xor(m, 1));
                m = fmaxf(m, __shfl_xor(m, 2));
                m = fmaxf(m, __shfl_xor(m, 4));
                m = fmaxf(m, __shfl_xor(m, 8));
                float s = 0.f;
#pragma unroll
                for (int nt = 0; nt < 4; ++nt) { v[nt] = __expf(v[nt] - m); s += v[nt]; }
                s += __shfl_xor(s, 1);
                s += __shfl_xor(s, 2);
                s += __shfl_xor(s, 4);
                s += __shfl_xor(s, 8);
                float inv = 1.0f / s;
#pragma unroll
                for (int nt = 0; nt < 4; ++nt)
                    SW[row * WV_STRIDE + nt * 16 + lo] = (__bf16)(v[nt] * inv);
            }
        }

        // ---------------- PV
        f32x4 pv[4][2];
#pragma unroll
        for (int mt = 0; mt < 4; ++mt)
#pragma unroll
            for (int nt = 0; nt < 2; ++nt) pv[mt][nt] = zz;
#pragma unroll
        for (int ks = 0; ks < 2; ++ks) {
            bf16x8 ap[4], bv[2];
#pragma unroll
            for (int mt = 0; mt < 4; ++mt)
                ap[mt] = *(const bf16x8*)&SW[(mt * 16 + lo) * WV_STRIDE + ks * 32 + hi * 8];
#pragma unroll
            for (int nt = 0; nt < 2; ++nt)
                bv[nt] = *(const bf16x8*)&VTs[(nt * 16 + lo) * WV_STRIDE + ks * 32 + hi * 8];
#pragma unroll
            for (int mt = 0; mt < 4; ++mt)
#pragma unroll
                for (int nt = 0; nt < 2; ++nt)
                    pv[mt][nt] = __builtin_amdgcn_mfma_f32_16x16x32_bf16(ap[mt], bv[nt], pv[mt][nt], 0, 0, 0);
        }
        // px -> shared PXS (own cols 32w..32w+31)
#pragma unroll
        for (int mt = 0; mt < 4; ++mt)
#pragma unroll
            for (int nt = 0; nt < 2; ++nt)
#pragma unroll
                for (int r = 0; r < 4; ++r)
                    PXS[(mt * 16 + hi * 4 + r) * PX_STRIDE + 32 * w + nt * 16 + lo] = (__bf16)pv[mt][nt][r];

        __syncthreads();

        // ---------------- proj (wave w -> out cols [32w, 32w+32))
        f32x4 po[4][2];
#pragma unroll
        for (int mt = 0; mt < 4; ++mt)
#pragma unroll
            for (int nt = 0; nt < 2; ++nt) po[mt][nt] = zz;
        const __bf16* wprow[2];
#pragma unroll
        for (int nt = 0; nt < 2; ++nt)
            wprow[nt] = wp + (size_t)(32 * w + nt * 16 + lo) * C_ + hi * 8;
#pragma unroll
        for (int ks = 0; ks < 4; ++ks) {
            bf16x8 apx[4], bw[2];
#pragma unroll
            for (int mt = 0; mt < 4; ++mt)
                apx[mt] = *(const bf16x8*)&PXS[(mt * 16 + lo) * PX_STRIDE + ks * 32 + hi * 8];
#pragma unroll
            for (int nt = 0; nt < 2; ++nt)
                bw[nt] = *(const bf16x8*)(wprow[nt] + ks * 32);
#pragma unroll
            for (int mt = 0; mt < 4; ++mt)
#pragma unroll
                for (int nt = 0; nt < 2; ++nt)
                    po[mt][nt] = __builtin_amdgcn_mfma_f32_16x16x32_bf16(apx[mt], bw[nt], po[mt][nt], 0, 0, 0);
        }
        float bp0 = bproj[32 * w + lo];
        float bp1 = bproj[32 * w + 16 + lo];
        float* outb = out + (size_t)b * TTOT * C_;
#pragma unroll
        for (int mt = 0; mt < 4; ++mt) {
#pragma unroll
            for (int r = 0; r < 4; ++r) {
                int row = mt * 16 + hi * 4 + r;
                int tok = (wi * 8 + (row >> 3)) * WIMG + wj * 8 + (row & 7);
                float* orow = outb + (size_t)tok * C_ + 32 * w + lo;
                orow[0]  = po[mt][0][r] + bp0;
                orow[16] = po[mt][1][r] + bp1;
            }
        }
    } else {
        // ================= token path: one block per (b,set) =================
        const int tb  = bx;
        const int b   = tb >> 1;
        const int set = tb & 1;
        const float* src = set ? (inter + (size_t)b * 100 * C_) : (det + (size_t)b * 100 * C_);
        __bf16* xs  = (__bf16*)(SMEM + TOK_XS_OFF);   // [100][136]: x, later px
        __bf16* qs  = (__bf16*)(SMEM + TOK_QS_OFF);   // [100][34]
        __bf16* ks2 = (__bf16*)(SMEM + TOK_KS_OFF);
        __bf16* vs2 = (__bf16*)(SMEM + TOK_VS_OFF);
        float* qkvT = qkvT_ws + (size_t)tb * 38400;

        for (int i = tid; i < 12800; i += 256) {
            int t = i >> 7, c = i & 127;
            xs[t * PX_STRIDE + c] = (__bf16)src[i];
        }
        __syncthreads();

        for (int idx = tid; idx < 38400; idx += 256) {
            int n = idx / 100;
            int t = idx - n * 100;
            float s = 0.f;
#pragma unroll
            for (int k = 0; k < 128; k += 8) {
                bf16x8 xv = *(const bf16x8*)&xs[t * PX_STRIDE + k];
                bf16x8 wv = *(const bf16x8*)&wq[n * C_ + k];
#pragma unroll
                for (int u = 0; u < 8; ++u) s += (float)xv[u] * (float)wv[u];
            }
            qkvT[idx] = s + bqkv[n];
        }
        __syncthreads();

        for (int h = 0; h < 4; ++h) {
            for (int i = tid; i < 3200; i += 256) {
                int nl = i / 100;
                int t = i - nl * 100;
                qs[t * TOK_STR + nl]  = (__bf16)qkvT[(32 * h + nl) * 100 + t];
                ks2[t * TOK_STR + nl] = (__bf16)qkvT[(128 + 32 * h + nl) * 100 + t];
                vs2[t * TOK_STR + nl] = (__bf16)qkvT[(256 + 32 * h + nl) * 100 + t];
            }
            __syncthreads();
            if (tid < 100) {
                int t = tid;
                float qreg[32];
#pragma unroll
                for (int d = 0; d < 32; ++d) qreg[d] = (float)qs[t * TOK_STR + d];
                float m = -1e30f;
                for (int j = 0; j < 100; ++j) {
                    float s = 0.f;
#pragma unroll
                    for (int d = 0; d < 32; ++d) s += qreg[d] * (float)ks2[j * TOK_STR + d];
                    m = fmaxf(m, s * SCALE);
                }
                float sum = 0.f;
                float acc32[32];
#pragma unroll
                for (int d = 0; d < 32; ++d) acc32[d] = 0.f;
                for (int j = 0; j < 100; ++j) {
                    float s = 0.f;
#pragma unroll
                    for (int d = 0; d < 32; ++d) s += qreg[d] * (float)ks2[j * TOK_STR + d];
                    float p = __expf(s * SCALE - m);
                    sum += p;
#pragma unroll
                    for (int d = 0; d < 32; ++d) acc32[d] += p * (float)vs2[j * TOK_STR + d];
                }
                float inv = 1.0f / sum;
#pragma unroll
                for (int d = 0; d < 32; ++d)
                    xs[t * PX_STRIDE + 32 * h + d] = (__bf16)(acc32[d] * inv);
            }
            __syncthreads();
        }

        for (int idx = tid; idx < 12800; idx += 256) {
            int t = idx >> 7, c = idx & 127;
            float s = 0.f;
#pragma unroll
            for (int k = 0; k < 128; k += 8) {
                bf16x8 a = *(const bf16x8*)&xs[t * PX_STRIDE + k];
                bf16x8 bwv = *(const bf16x8*)&wp[c * C_ + k];
#pragma unroll
                for (int u = 0; u < 8; ++u) s += (float)a[u] * (float)bwv[u];
            }
            out[((size_t)b * TTOT + NPATCH + set * 100 + t) * C_ + c] = s + bproj[c];
        }
    }
}

// ---------------------------------------------------------------- launch
extern "C" void kernel_launch(void* const* d_in, const int* in_sizes, int n_in,
                              void* d_out, int out_size, void* d_ws, size_t ws_size,
                              hipStream_t stream) {
    const float* x         = (const float*)d_in[0];
    const float* det       = (const float*)d_in[1];
    const float* inter     = (const float*)d_in[2];
    const float* mask      = (const float*)d_in[3];
    const float* Wq        = (const float*)d_in[4];
    const float* bq        = (const float*)d_in[5];
    const float* Wp        = (const float*)d_in[6];
    const float* bp        = (const float*)d_in[7];
    const float* rel_table = (const float*)d_in[8];
    const int*   rel_index = (const int*)d_in[9];
    float* out = (float*)d_out;

    char* ws = (char*)d_ws;
    unsigned short* wq_b = (unsigned short*)(ws + WS_WQ);
    unsigned short* wp_b = (unsigned short*)(ws + WS_WP);
    float* biasT         = (float*)(ws + WS_BIAS);
    float* qkvT_ws       = (float*)(ws + WS_QKVTOK);

    prep_kernel<<<320, 256, 0, stream>>>(Wq, Wp, rel_table, rel_index, wq_b, wp_b, biasT);
    fused_kernel<<<4104, 256, 0, stream>>>(x, det, inter, mask, wq_b, bq, wp_b, bp,
                                           biasT, qkvT_ws, out);
}

// Round 4
// 606.286 us; speedup vs baseline: 1.1913x; 1.1619x over previous
//
#include <hip/hip_runtime.h>

#define B_    4
#define HIMG  256
#define WIMG  256
#define C_    128
#define NH_   4
#define WS8   8
#define L_    64
#define NWX   32
#define NPATCH (HIMG*WIMG)           // 65536
#define TTOT  (NPATCH + 200)         // 65736
#define SCALE 0.17677669529663689f   // 32^-0.5

typedef __bf16 bf16x8 __attribute__((ext_vector_type(8)));
typedef __bf16 bf16x4 __attribute__((ext_vector_type(4)));
typedef float  f32x4  __attribute__((ext_vector_type(4)));

// ---- shared-memory layout (54272 B total) ----
// per-wave scratch block @ w*WV_BYTES:
//   [64][72] bf16  Q (cols 0..31) | K (cols 32..63); P overlays cols 0..63
//   [32][68] bf16  V^T  @ +9216
// after PV (barrier): px exchange [64][136] bf16 @ offset 0 (17408 B, spans
// wave0+part of wave1 scratch — all dead by then). 2 barriers total.
#define SMEM_BYTES 54272
#define QK_STRIDE  72                // 144 B rows: 16B-mult, 2-way banks
#define KOFF       32
#define VT_OFF     9216              // bytes
#define VT_STRIDE  68                // 136 B rows: 8B-mult, 2-way banks
#define WV_BYTES   13568             // 9216 + 32*68*2
#define PX_STRIDE  136               // 272 B rows
// token-block reuse of the same SMEM (47600 B used):
#define TOK_XS_OFF 0
#define TOK_QS_OFF 27200
#define TOK_KS_OFF 34000
#define TOK_VS_OFF 40800
#define TOK_STR    34

// ---- workspace layout (bytes) ----
#define WS_WQ     0          // 384*128 bf16 = 98304
#define WS_WP     98304      // 128*128 bf16 = 32768
#define WS_BIAS   131072     // 4*64*64 f32  = 65536
#define WS_QKVTOK 196608     // 8 * 38400 f32 = 1228800

// ---------------------------------------------------------------- prep
__global__ __launch_bounds__(256)
void prep_kernel(const float* __restrict__ Wq, const float* __restrict__ Wp,
                 const float* __restrict__ rel_table, const int* __restrict__ rel_index,
                 unsigned short* __restrict__ wq_b, unsigned short* __restrict__ wp_b,
                 float* __restrict__ biasT) {
    int id = blockIdx.x * 256 + threadIdx.x;
    if (id < 49152) {
        __bf16 v = (__bf16)Wq[id];
        wq_b[id] = *(unsigned short*)&v;
    } else if (id < 65536) {
        int i = id - 49152;
        __bf16 v = (__bf16)Wp[i];
        wp_b[i] = *(unsigned short*)&v;
    } else if (id < 81920) {
        int t = id - 65536;
        int h = t >> 12, ij = t & 4095;
        biasT[h * 4096 + ij] = rel_table[rel_index[ij] * 4 + h];
    }
}

// ---------------------------------------------------------------- fused kernel
// blocks 0..7: token path (b,set).  blocks 8..4103: window path (XCD-grouped).
__global__ __launch_bounds__(256, 1)
void fused_kernel(const float* __restrict__ x, const float* __restrict__ det,
                  const float* __restrict__ inter, const float* __restrict__ mask,
                  const unsigned short* __restrict__ wq_u, const float* __restrict__ bqkv,
                  const unsigned short* __restrict__ wp_u, const float* __restrict__ bproj,
                  const float* __restrict__ biasT, float* __restrict__ qkvT_ws,
                  float* __restrict__ out) {
    __shared__ __align__(16) char SMEM[SMEM_BYTES];
    const __bf16* wq = (const __bf16*)wq_u;
    const __bf16* wp = (const __bf16*)wp_u;
    const int tid = threadIdx.x;
    const int bx = blockIdx.x;
    const f32x4 zz = {0.f, 0.f, 0.f, 0.f};

    if (bx >= 8) {
        // ================= window path =================
        // XCD remap: 4 batch-copies of one window land on one XCD back-to-back
        // -> 16KB mask slice L2-hot (FETCH 99->76MB measured).
        const int wbx = bx - 8;
        const int xcd = wbx & 7;
        const int grp = wbx >> 3;
        const int b   = grp & 3;
        const int widx = xcd + 8 * (grp >> 2);   // 0..1023
        const int wi = widx >> 5;
        const int wj = widx & 31;

        const int w  = tid >> 6;          // wave == head
        const int l  = tid & 63;
        const int lo = l & 15;
        const int hi = l >> 4;

        __bf16* SW  = (__bf16*)(SMEM + w * WV_BYTES);            // [64][72]: Q|K, later P
        __bf16* VTs = (__bf16*)(SMEM + w * WV_BYTES + VT_OFF);   // [32][68]: V^T
        __bf16* PXU = (__bf16*)SMEM;                             // [64][136]: px union

        // ---------------- phase 1: QKV accumulators
        const float* xw = x + (((size_t)(b * HIMG) + wi * WS8) * WIMG + wj * WS8) * C_;
        const float* arow[4];
#pragma unroll
        for (int mt = 0; mt < 4; ++mt) {
            int t = mt * 16 + lo;
            arow[mt] = xw + ((size_t)(t >> 3) * WIMG + (t & 7)) * C_ + hi * 8;
        }
        int nbase[6];
        const __bf16* brow[6];
#pragma unroll
        for (int g = 0; g < 3; ++g) {
            nbase[2 * g]     = g * 128 + 32 * w;
            nbase[2 * g + 1] = g * 128 + 32 * w + 16;
        }
#pragma unroll
        for (int nt = 0; nt < 6; ++nt)
            brow[nt] = wq + (size_t)(nbase[nt] + lo) * C_ + hi * 8;

        f32x4 acc[4][6];
#pragma unroll
        for (int mt = 0; mt < 4; ++mt)
#pragma unroll
            for (int nt = 0; nt < 6; ++nt) acc[mt][nt] = zz;

#pragma unroll
        for (int ks = 0; ks < 4; ++ks) {
            bf16x8 a[4], bb[6];
#pragma unroll
            for (int mt = 0; mt < 4; ++mt) {
                const float* pa = arow[mt] + ks * 32;
                float4 v0 = *(const float4*)pa;
                float4 v1 = *(const float4*)(pa + 4);
                bf16x8 av;
                av[0] = (__bf16)v0.x; av[1] = (__bf16)v0.y; av[2] = (__bf16)v0.z; av[3] = (__bf16)v0.w;
                av[4] = (__bf16)v1.x; av[5] = (__bf16)v1.y; av[6] = (__bf16)v1.z; av[7] = (__bf16)v1.w;
                a[mt] = av;
            }
#pragma unroll
            for (int nt = 0; nt < 6; ++nt)
                bb[nt] = *(const bf16x8*)(brow[nt] + ks * 32);
#pragma unroll
            for (int mt = 0; mt < 4; ++mt)
#pragma unroll
                for (int nt = 0; nt < 6; ++nt)
                    acc[mt][nt] = __builtin_amdgcn_mfma_f32_16x16x32_bf16(a[mt], bb[nt], acc[mt][nt], 0, 0, 0);
        }

        // ---------------- scatter Q, K, V^T to LDS (write all, then read)
#pragma unroll
        for (int nt = 0; nt < 6; ++nt) {
            float bq = bqkv[nbase[nt] + lo];
            if (nt < 2) {
                int col = nt * 16 + lo;
#pragma unroll
                for (int mt = 0; mt < 4; ++mt)
#pragma unroll
                    for (int r = 0; r < 4; ++r)
                        SW[(mt * 16 + hi * 4 + r) * QK_STRIDE + col] = (__bf16)(acc[mt][nt][r] + bq);
            } else if (nt < 4) {
                int col = KOFF + (nt - 2) * 16 + lo;
#pragma unroll
                for (int mt = 0; mt < 4; ++mt)
#pragma unroll
                    for (int r = 0; r < 4; ++r)
                        SW[(mt * 16 + hi * 4 + r) * QK_STRIDE + col] = (__bf16)(acc[mt][nt][r] + bq);
            } else {
                int d = (nt - 4) * 16 + lo;
#pragma unroll
                for (int mt = 0; mt < 4; ++mt) {
                    bf16x4 vv;
#pragma unroll
                    for (int r = 0; r < 4; ++r) vv[r] = (__bf16)(acc[mt][nt][r] + bq);
                    *(bf16x4*)&VTs[d * VT_STRIDE + mt * 16 + hi * 4] = vv;
                }
            }
        }

        bf16x8 aq[4], bk[4];
#pragma unroll
        for (int mt = 0; mt < 4; ++mt)
            aq[mt] = *(const bf16x8*)&SW[(mt * 16 + lo) * QK_STRIDE + hi * 8];
#pragma unroll
        for (int nt = 0; nt < 4; ++nt)
            bk[nt] = *(const bf16x8*)&SW[(nt * 16 + lo) * QK_STRIDE + KOFF + hi * 8];

        // ---------------- QK^T
        f32x4 lg[4][4];
#pragma unroll
        for (int mt = 0; mt < 4; ++mt)
#pragma unroll
            for (int nt = 0; nt < 4; ++nt)
                lg[mt][nt] = __builtin_amdgcn_mfma_f32_16x16x32_bf16(aq[mt], bk[nt], zz, 0, 0, 0);

        // ---------------- softmax, P -> scratch (overlays Q/K; both in regs)
        const float* biasH = biasT + w * 4096;
        const float* maskW = mask + (size_t)(wi * NWX + wj) * 4096;
#pragma unroll
        for (int mt = 0; mt < 4; ++mt) {
#pragma unroll
            for (int r = 0; r < 4; ++r) {
                int row = mt * 16 + hi * 4 + r;
                float v[4];
                float m = -1e30f;
#pragma unroll
                for (int nt = 0; nt < 4; ++nt) {
                    int col = nt * 16 + lo;
                    float t = lg[mt][nt][r] * SCALE + biasH[row * 64 + col] + maskW[row * 64 + col];
                    v[nt] = t;
                    m = fmaxf(m, t);
                }
                m = fmaxf(m, __shfl_xor(m, 1));
                m = fmaxf(m, __shfl_xor(m, 2));
                m = fmaxf(m, __shfl_xor(m, 4));
                m = fmaxf(m, __shfl_xor(m, 8));
                float s = 0.f;
#pragma unroll
                for (int nt = 0; nt < 4; ++nt) { v[nt] = __expf(v[nt] - m); s += v[nt]; }
                s += __shfl_xor(s, 1);
                s += __shfl_xor(s, 2);
                s += __shfl_xor(s, 4);
                s += __shfl_xor(s, 8);
                float inv = 1.0f / s;
#pragma unroll
                for (int nt = 0; nt < 4; ++nt)
                    SW[row * QK_STRIDE + nt * 16 + lo] = (__bf16)(v[nt] * inv);
            }
        }

        // ---------------- PV
        f32x4 pv[4][2];
#pragma unroll
        for (int mt = 0; mt < 4; ++mt)
#pragma unroll
            for (int nt = 0; nt < 2; ++nt) pv[mt][nt] = zz;
#pragma unroll
        for (int ks = 0; ks < 2; ++ks) {
            bf16x8 ap[4], bv[2];
#pragma unroll
            for (int mt = 0; mt < 4; ++mt)
                ap[mt] = *(const bf16x8*)&SW[(mt * 16 + lo) * QK_STRIDE + ks * 32 + hi * 8];
#pragma unroll
            for (int nt = 0; nt < 2; ++nt) {
                bf16x4 b0 = *(const bf16x4*)&VTs[(nt * 16 + lo) * VT_STRIDE + ks * 32 + hi * 8];
                bf16x4 b1 = *(const bf16x4*)&VTs[(nt * 16 + lo) * VT_STRIDE + ks * 32 + hi * 8 + 4];
                bf16x8 bb;
#pragma unroll
                for (int u = 0; u < 4; ++u) { bb[u] = b0[u]; bb[u + 4] = b1[u]; }
                bv[nt] = bb;
            }
#pragma unroll
            for (int mt = 0; mt < 4; ++mt)
#pragma unroll
                for (int nt = 0; nt < 2; ++nt)
                    pv[mt][nt] = __builtin_amdgcn_mfma_f32_16x16x32_bf16(ap[mt], bv[nt], pv[mt][nt], 0, 0, 0);
        }

        // ---------------- px exchange through scratch union
        __syncthreads();   // all waves done reading their scratch
#pragma unroll
        for (int mt = 0; mt < 4; ++mt)
#pragma unroll
            for (int nt = 0; nt < 2; ++nt)
#pragma unroll
                for (int r = 0; r < 4; ++r)
                    PXU[(mt * 16 + hi * 4 + r) * PX_STRIDE + 32 * w + nt * 16 + lo] = (__bf16)pv[mt][nt][r];
        __syncthreads();

        // ---------------- proj (wave w -> out cols [32w, 32w+32))
        f32x4 po[4][2];
#pragma unroll
        for (int mt = 0; mt < 4; ++mt)
#pragma unroll
            for (int nt = 0; nt < 2; ++nt) po[mt][nt] = zz;
        const __bf16* wprow[2];
#pragma unroll
        for (int nt = 0; nt < 2; ++nt)
            wprow[nt] = wp + (size_t)(32 * w + nt * 16 + lo) * C_ + hi * 8;
#pragma unroll
        for (int ks = 0; ks < 4; ++ks) {
            bf16x8 apx[4], bw[2];
#pragma unroll
            for (int mt = 0; mt < 4; ++mt)
                apx[mt] = *(const bf16x8*)&PXU[(mt * 16 + lo) * PX_STRIDE + ks * 32 + hi * 8];
#pragma unroll
            for (int nt = 0; nt < 2; ++nt)
                bw[nt] = *(const bf16x8*)(wprow[nt] + ks * 32);
#pragma unroll
            for (int mt = 0; mt < 4; ++mt)
#pragma unroll
                for (int nt = 0; nt < 2; ++nt)
                    po[mt][nt] = __builtin_amdgcn_mfma_f32_16x16x32_bf16(apx[mt], bw[nt], po[mt][nt], 0, 0, 0);
        }
        float bp0 = bproj[32 * w + lo];
        float bp1 = bproj[32 * w + 16 + lo];
        float* outb = out + (size_t)b * TTOT * C_;
#pragma unroll
        for (int mt = 0; mt < 4; ++mt) {
#pragma unroll
            for (int r = 0; r < 4; ++r) {
                int row = mt * 16 + hi * 4 + r;
                int tok = (wi * 8 + (row >> 3)) * WIMG + wj * 8 + (row & 7);
                float* orow = outb + (size_t)tok * C_ + 32 * w + lo;
                orow[0]  = po[mt][0][r] + bp0;
                orow[16] = po[mt][1][r] + bp1;
            }
        }
    } else {
        // ================= token path: one block per (b,set) =================
        const int tb  = bx;
        const int b   = tb >> 1;
        const int set = tb & 1;
        const float* src = set ? (inter + (size_t)b * 100 * C_) : (det + (size_t)b * 100 * C_);
        __bf16* xs  = (__bf16*)(SMEM + TOK_XS_OFF);   // [100][136]: x, later px
        __bf16* qs  = (__bf16*)(SMEM + TOK_QS_OFF);   // [100][34]
        __bf16* ks2 = (__bf16*)(SMEM + TOK_KS_OFF);
        __bf16* vs2 = (__bf16*)(SMEM + TOK_VS_OFF);
        float* qkvT = qkvT_ws + (size_t)tb * 38400;

        for (int i = tid; i < 12800; i += 256) {
            int t = i >> 7, c = i & 127;
            xs[t * PX_STRIDE + c] = (__bf16)src[i];
        }
        __syncthreads();

        for (int idx = tid; idx < 38400; idx += 256) {
            int n = idx / 100;
            int t = idx - n * 100;
            float s = 0.f;
#pragma unroll
            for (int k = 0; k < 128; k += 8) {
                bf16x8 xv = *(const bf16x8*)&xs[t * PX_STRIDE + k];
                bf16x8 wv = *(const bf16x8*)&wq[n * C_ + k];
#pragma unroll
                for (int u = 0; u < 8; ++u) s += (float)xv[u] * (float)wv[u];
            }
            qkvT[idx] = s + bqkv[n];
        }
        __syncthreads();

        for (int h = 0; h < 4; ++h) {
            for (int i = tid; i < 3200; i += 256) {
                int nl = i / 100;
                int t = i - nl * 100;
                qs[t * TOK_STR + nl]  = (__bf16)qkvT[(32 * h + nl) * 100 + t];
                ks2[t * TOK_STR + nl] = (__bf16)qkvT[(128 + 32 * h + nl) * 100 + t];
                vs2[t * TOK_STR + nl] = (__bf16)qkvT[(256 + 32 * h + nl) * 100 + t];
            }
            __syncthreads();
            if (tid < 100) {
                int t = tid;
                float qreg[32];
#pragma unroll
                for (int d = 0; d < 32; ++d) qreg[d] = (float)qs[t * TOK_STR + d];
                float m = -1e30f;
                for (int j = 0; j < 100; ++j) {
                    float s = 0.f;
#pragma unroll
                    for (int d = 0; d < 32; ++d) s += qreg[d] * (float)ks2[j * TOK_STR + d];
                    m = fmaxf(m, s * SCALE);
                }
                float sum = 0.f;
                float acc32[32];
#pragma unroll
                for (int d = 0; d < 32; ++d) acc32[d] = 0.f;
                for (int j = 0; j < 100; ++j) {
                    float s = 0.f;
#pragma unroll
                    for (int d = 0; d < 32; ++d) s += qreg[d] * (float)ks2[j * TOK_STR + d];
                    float p = __expf(s * SCALE - m);
                    sum += p;
#pragma unroll
                    for (int d = 0; d < 32; ++d) acc32[d] += p * (float)vs2[j * TOK_STR + d];
                }
                float inv = 1.0f / sum;
#pragma unroll
                for (int d = 0; d < 32; ++d)
                    xs[t * PX_STRIDE + 32 * h + d] = (__bf16)(acc32[d] * inv);
            }
            __syncthreads();
        }

        for (int idx = tid; idx < 12800; idx += 256) {
            int t = idx >> 7, c = idx & 127;
            float s = 0.f;
#pragma unroll
            for (int k = 0; k < 128; k += 8) {
                bf16x8 a = *(const bf16x8*)&xs[t * PX_STRIDE + k];
                bf16x8 bwv = *(const bf16x8*)&wp[c * C_ + k];
#pragma unroll
                for (int u = 0; u < 8; ++u) s += (float)a[u] * (float)bwv[u];
            }
            out[((size_t)b * TTOT + NPATCH + set * 100 + t) * C_ + c] = s + bproj[c];
        }
    }
}

// ---------------------------------------------------------------- launch
extern "C" void kernel_launch(void* const* d_in, const int* in_sizes, int n_in,
                              void* d_out, int out_size, void* d_ws, size_t ws_size,
                              hipStream_t stream) {
    const float* x         = (const float*)d_in[0];
    const float* det       = (const float*)d_in[1];
    const float* inter     = (const float*)d_in[2];
    const float* mask      = (const float*)d_in[3];
    const float* Wq        = (const float*)d_in[4];
    const float* bq        = (const float*)d_in[5];
    const float* Wp        = (const float*)d_in[6];
    const float* bp        = (const float*)d_in[7];
    const float* rel_table = (const float*)d_in[8];
    const int*   rel_index = (const int*)d_in[9];
    float* out = (float*)d_out;

    char* ws = (char*)d_ws;
    unsigned short* wq_b = (unsigned short*)(ws + WS_WQ);
    unsigned short* wp_b = (unsigned short*)(ws + WS_WP);
    float* biasT         = (float*)(ws + WS_BIAS);
    float* qkvT_ws       = (float*)(ws + WS_QKVTOK);

    prep_kernel<<<320, 256, 0, stream>>>(Wq, Wp, rel_table, rel_index, wq_b, wp_b, biasT);
    fused_kernel<<<4104, 256, 0, stream>>>(x, det, inter, mask, wq_b, bq, wp_b, bp,
                                           biasT, qkvT_ws, out);
}

// Round 5
// 285.584 us; speedup vs baseline: 2.5290x; 2.1230x over previous
//
#include <hip/hip_runtime.h>

#define B_    4
#define HIMG  256
#define WIMG  256
#define C_    128
#define NH_   4
#define WS8   8
#define L_    64
#define NWX   32
#define NPATCH (HIMG*WIMG)           // 65536
#define TTOT  (NPATCH + 200)         // 65736
#define SCALE 0.17677669529663689f   // 32^-0.5

typedef __bf16 bf16x8 __attribute__((ext_vector_type(8)));
typedef __bf16 bf16x4 __attribute__((ext_vector_type(4)));
typedef float  f32x4  __attribute__((ext_vector_type(4)));

// ---- shared memory: two windows per block, 54272 B each ----
// per-window region (char offset win*54272):
//   per-wave scratch @ w*13568: [64][72] bf16 Q(cols 0..31)|K(cols 32..63), P overlays
//                               [32][68] bf16 V^T @ +9216
//   px exchange [64][136] bf16 overlays offset 0 after barrier
#define WIN_BYTES  54272
#define SMEM_BYTES (2*WIN_BYTES)     // 108544 -> 1 block/CU, 8 waves forced co-resident
#define QK_STRIDE  72
#define KOFF       32
#define VT_OFF     9216
#define VT_STRIDE  68
#define WV_BYTES   13568
#define PX_STRIDE  136

// ---- workspace layout (bytes) ----
#define WS_WQ     0          // 384*128 bf16 = 98304
#define WS_WP     98304      // 128*128 bf16 = 32768
#define WS_BIAS   131072     // 4*64*64 f32  = 65536
#define WS_QKVTOK 196608     // 800*384 f32  = 1228800

// ---------------------------------------------------------------- prep
__global__ __launch_bounds__(256)
void prep_kernel(const float* __restrict__ Wq, const float* __restrict__ Wp,
                 const float* __restrict__ rel_table, const int* __restrict__ rel_index,
                 unsigned short* __restrict__ wq_b, unsigned short* __restrict__ wp_b,
                 float* __restrict__ biasT) {
    int id = blockIdx.x * 256 + threadIdx.x;
    if (id < 49152) {
        __bf16 v = (__bf16)Wq[id];
        wq_b[id] = *(unsigned short*)&v;
    } else if (id < 65536) {
        int i = id - 49152;
        __bf16 v = (__bf16)Wp[i];
        wp_b[i] = *(unsigned short*)&v;
    } else if (id < 81920) {
        int t = id - 65536;
        int h = t >> 12, ij = t & 4095;
        biasT[h * 4096 + ij] = rel_table[rel_index[ij] * 4 + h];
    }
}

// ---------------------------------------------------------------- window kernel
// 512 threads = 8 waves = 2 windows x 4 heads. Forces 2 waves/SIMD residency.
__global__ __launch_bounds__(512, 2)
void win2_kernel(const float* __restrict__ x, const float* __restrict__ mask,
                 const unsigned short* __restrict__ wq_u, const float* __restrict__ bqkv,
                 const unsigned short* __restrict__ wp_u, const float* __restrict__ bproj,
                 const float* __restrict__ biasT, float* __restrict__ out) {
    __shared__ __align__(16) char SMEM[SMEM_BYTES];
    const __bf16* wq = (const __bf16*)wq_u;
    const __bf16* wp = (const __bf16*)wp_u;
    const int tid = threadIdx.x;
    const f32x4 zz = {0.f, 0.f, 0.f, 0.f};

    const int win = tid >> 8;            // window-in-block
    const int w   = (tid >> 6) & 3;      // wave-in-window == head
    const int l   = tid & 63;
    const int lo  = l & 15;
    const int hi  = l >> 4;

    const int gw = blockIdx.x * 2 + win; // 0..4095, linear: consecutive wj -> x locality
    const int b  = gw >> 10;
    const int wi = (gw >> 5) & 31;
    const int wj = gw & 31;

    char* WB = SMEM + win * WIN_BYTES;
    __bf16* SW  = (__bf16*)(WB + w * WV_BYTES);            // [64][72]: Q|K, later P
    __bf16* VTs = (__bf16*)(WB + w * WV_BYTES + VT_OFF);   // [32][68]: V^T
    __bf16* PXU = (__bf16*)WB;                             // [64][136]: px union

    // ---------------- phase 1: QKV accumulators
    const float* xw = x + (((size_t)(b * HIMG) + wi * WS8) * WIMG + wj * WS8) * C_;
    const float* arow[4];
#pragma unroll
    for (int mt = 0; mt < 4; ++mt) {
        int t = mt * 16 + lo;
        arow[mt] = xw + ((size_t)(t >> 3) * WIMG + (t & 7)) * C_ + hi * 8;
    }
    int nbase[6];
    const __bf16* brow[6];
#pragma unroll
    for (int g = 0; g < 3; ++g) {
        nbase[2 * g]     = g * 128 + 32 * w;
        nbase[2 * g + 1] = g * 128 + 32 * w + 16;
    }
#pragma unroll
    for (int nt = 0; nt < 6; ++nt)
        brow[nt] = wq + (size_t)(nbase[nt] + lo) * C_ + hi * 8;

    f32x4 acc[4][6];
#pragma unroll
    for (int mt = 0; mt < 4; ++mt)
#pragma unroll
        for (int nt = 0; nt < 6; ++nt) acc[mt][nt] = zz;

#pragma unroll
    for (int ks = 0; ks < 4; ++ks) {
        bf16x8 a[4], bb[6];
#pragma unroll
        for (int mt = 0; mt < 4; ++mt) {
            const float* pa = arow[mt] + ks * 32;
            float4 v0 = *(const float4*)pa;
            float4 v1 = *(const float4*)(pa + 4);
            bf16x8 av;
            av[0] = (__bf16)v0.x; av[1] = (__bf16)v0.y; av[2] = (__bf16)v0.z; av[3] = (__bf16)v0.w;
            av[4] = (__bf16)v1.x; av[5] = (__bf16)v1.y; av[6] = (__bf16)v1.z; av[7] = (__bf16)v1.w;
            a[mt] = av;
        }
#pragma unroll
        for (int nt = 0; nt < 6; ++nt)
            bb[nt] = *(const bf16x8*)(brow[nt] + ks * 32);
#pragma unroll
        for (int mt = 0; mt < 4; ++mt)
#pragma unroll
            for (int nt = 0; nt < 6; ++nt)
                acc[mt][nt] = __builtin_amdgcn_mfma_f32_16x16x32_bf16(a[mt], bb[nt], acc[mt][nt], 0, 0, 0);
    }

    // ---------------- scatter Q, K, V^T to LDS (write all, then read)
#pragma unroll
    for (int nt = 0; nt < 6; ++nt) {
        float bq = bqkv[nbase[nt] + lo];
        if (nt < 2) {
            int col = nt * 16 + lo;
#pragma unroll
            for (int mt = 0; mt < 4; ++mt)
#pragma unroll
                for (int r = 0; r < 4; ++r)
                    SW[(mt * 16 + hi * 4 + r) * QK_STRIDE + col] = (__bf16)(acc[mt][nt][r] + bq);
        } else if (nt < 4) {
            int col = KOFF + (nt - 2) * 16 + lo;
#pragma unroll
            for (int mt = 0; mt < 4; ++mt)
#pragma unroll
                for (int r = 0; r < 4; ++r)
                    SW[(mt * 16 + hi * 4 + r) * QK_STRIDE + col] = (__bf16)(acc[mt][nt][r] + bq);
        } else {
            int d = (nt - 4) * 16 + lo;
#pragma unroll
            for (int mt = 0; mt < 4; ++mt) {
                bf16x4 vv;
#pragma unroll
                for (int r = 0; r < 4; ++r) vv[r] = (__bf16)(acc[mt][nt][r] + bq);
                *(bf16x4*)&VTs[d * VT_STRIDE + mt * 16 + hi * 4] = vv;
            }
        }
    }

    bf16x8 aq[4], bk[4];
#pragma unroll
    for (int mt = 0; mt < 4; ++mt)
        aq[mt] = *(const bf16x8*)&SW[(mt * 16 + lo) * QK_STRIDE + hi * 8];
#pragma unroll
    for (int nt = 0; nt < 4; ++nt)
        bk[nt] = *(const bf16x8*)&SW[(nt * 16 + lo) * QK_STRIDE + KOFF + hi * 8];

    // ---------------- QK^T
    f32x4 lg[4][4];
#pragma unroll
    for (int mt = 0; mt < 4; ++mt)
#pragma unroll
        for (int nt = 0; nt < 4; ++nt)
            lg[mt][nt] = __builtin_amdgcn_mfma_f32_16x16x32_bf16(aq[mt], bk[nt], zz, 0, 0, 0);

    // ---------------- softmax, P -> scratch (overlays Q/K; both in regs)
    const float* biasH = biasT + w * 4096;
    const float* maskW = mask + (size_t)(wi * NWX + wj) * 4096;
#pragma unroll
    for (int mt = 0; mt < 4; ++mt) {
#pragma unroll
        for (int r = 0; r < 4; ++r) {
            int row = mt * 16 + hi * 4 + r;
            float v[4];
            float m = -1e30f;
#pragma unroll
            for (int nt = 0; nt < 4; ++nt) {
                int col = nt * 16 + lo;
                float t = lg[mt][nt][r] * SCALE + biasH[row * 64 + col] + maskW[row * 64 + col];
                v[nt] = t;
                m = fmaxf(m, t);
            }
            m = fmaxf(m, __shfl_xor(m, 1));
            m = fmaxf(m, __shfl_xor(m, 2));
            m = fmaxf(m, __shfl_xor(m, 4));
            m = fmaxf(m, __shfl_xor(m, 8));
            float s = 0.f;
#pragma unroll
            for (int nt = 0; nt < 4; ++nt) { v[nt] = __expf(v[nt] - m); s += v[nt]; }
            s += __shfl_xor(s, 1);
            s += __shfl_xor(s, 2);
            s += __shfl_xor(s, 4);
            s += __shfl_xor(s, 8);
            float inv = 1.0f / s;
#pragma unroll
            for (int nt = 0; nt < 4; ++nt)
                SW[row * QK_STRIDE + nt * 16 + lo] = (__bf16)(v[nt] * inv);
        }
    }

    // ---------------- PV
    f32x4 pv[4][2];
#pragma unroll
    for (int mt = 0; mt < 4; ++mt)
#pragma unroll
        for (int nt = 0; nt < 2; ++nt) pv[mt][nt] = zz;
#pragma unroll
    for (int ks = 0; ks < 2; ++ks) {
        bf16x8 ap[4], bv[2];
#pragma unroll
        for (int mt = 0; mt < 4; ++mt)
            ap[mt] = *(const bf16x8*)&SW[(mt * 16 + lo) * QK_STRIDE + ks * 32 + hi * 8];
#pragma unroll
        for (int nt = 0; nt < 2; ++nt) {
            bf16x4 b0 = *(const bf16x4*)&VTs[(nt * 16 + lo) * VT_STRIDE + ks * 32 + hi * 8];
            bf16x4 b1 = *(const bf16x4*)&VTs[(nt * 16 + lo) * VT_STRIDE + ks * 32 + hi * 8 + 4];
            bf16x8 bb;
#pragma unroll
            for (int u = 0; u < 4; ++u) { bb[u] = b0[u]; bb[u + 4] = b1[u]; }
            bv[nt] = bb;
        }
#pragma unroll
        for (int mt = 0; mt < 4; ++mt)
#pragma unroll
            for (int nt = 0; nt < 2; ++nt)
                pv[mt][nt] = __builtin_amdgcn_mfma_f32_16x16x32_bf16(ap[mt], bv[nt], pv[mt][nt], 0, 0, 0);
    }

    // ---------------- px exchange through per-window scratch union
    __syncthreads();   // all waves done reading their scratch
#pragma unroll
    for (int mt = 0; mt < 4; ++mt)
#pragma unroll
        for (int nt = 0; nt < 2; ++nt)
#pragma unroll
            for (int r = 0; r < 4; ++r)
                PXU[(mt * 16 + hi * 4 + r) * PX_STRIDE + 32 * w + nt * 16 + lo] = (__bf16)pv[mt][nt][r];
    __syncthreads();

    // ---------------- proj (wave w -> out cols [32w, 32w+32))
    f32x4 po[4][2];
#pragma unroll
    for (int mt = 0; mt < 4; ++mt)
#pragma unroll
        for (int nt = 0; nt < 2; ++nt) po[mt][nt] = zz;
    const __bf16* wprow[2];
#pragma unroll
    for (int nt = 0; nt < 2; ++nt)
        wprow[nt] = wp + (size_t)(32 * w + nt * 16 + lo) * C_ + hi * 8;
#pragma unroll
    for (int ks = 0; ks < 4; ++ks) {
        bf16x8 apx[4], bw[2];
#pragma unroll
        for (int mt = 0; mt < 4; ++mt)
            apx[mt] = *(const bf16x8*)&PXU[(mt * 16 + lo) * PX_STRIDE + ks * 32 + hi * 8];
#pragma unroll
        for (int nt = 0; nt < 2; ++nt)
            bw[nt] = *(const bf16x8*)(wprow[nt] + ks * 32);
#pragma unroll
        for (int mt = 0; mt < 4; ++mt)
#pragma unroll
            for (int nt = 0; nt < 2; ++nt)
                po[mt][nt] = __builtin_amdgcn_mfma_f32_16x16x32_bf16(apx[mt], bw[nt], po[mt][nt], 0, 0, 0);
    }
    float bp0 = bproj[32 * w + lo];
    float bp1 = bproj[32 * w + 16 + lo];
    float* outb = out + (size_t)b * TTOT * C_;
#pragma unroll
    for (int mt = 0; mt < 4; ++mt) {
#pragma unroll
        for (int r = 0; r < 4; ++r) {
            int row = mt * 16 + hi * 4 + r;
            int tok = (wi * 8 + (row >> 3)) * WIMG + wj * 8 + (row & 7);
            float* orow = outb + (size_t)tok * C_ + 32 * w + lo;
            orow[0]  = po[mt][0][r] + bp0;
            orow[16] = po[mt][1][r] + bp1;
        }
    }
}

// ---------------------------------------------------------------- token path (det/inter)
__global__ __launch_bounds__(256)
void tok_qkv_kernel(const float* __restrict__ det, const float* __restrict__ inter,
                    const float* __restrict__ Wq, const float* __restrict__ bq,
                    float* __restrict__ qkv_tok) {
    __shared__ float xs[128];
    int rid = blockIdx.x;                // 0..799
    int b = rid / 200, rem = rid % 200;
    const float* src = (rem < 100) ? det + (size_t)(b * 100 + rem) * 128
                                   : inter + (size_t)(b * 100 + rem - 100) * 128;
    int tid = threadIdx.x;
    if (tid < 128) xs[tid] = src[tid];
    __syncthreads();
    for (int n = tid; n < 384; n += 256) {
        const float* wr = Wq + (size_t)n * 128;
        float s = 0.f;
#pragma unroll 8
        for (int k = 0; k < 128; ++k) s += xs[k] * wr[k];
        qkv_tok[(size_t)rid * 384 + n] = s + bq[n];
    }
}

__global__ __launch_bounds__(256)
void tok_attn_kernel(const float* __restrict__ qkv_tok, float* __restrict__ px_tok) {
    __shared__ float qs[100 * 32];
    __shared__ float ks2[100 * 32];
    __shared__ float vs2[100 * 32];
    __shared__ float lg2[100 * 101];
    int bid = blockIdx.x;        // bs*4 + h
    int h  = bid & 3;
    int bs = bid >> 2;           // 0..7
    int rid0 = bs * 100;
    int tid = threadIdx.x;
    for (int i = tid; i < 3200; i += 256) {
        int t = i >> 5, d = i & 31;
        const float* base = qkv_tok + (size_t)(rid0 + t) * 384 + 32 * h + d;
        qs[i]  = base[0];
        ks2[i] = base[128];
        vs2[i] = base[256];
    }
    __syncthreads();
    for (int idx = tid; idx < 10000; idx += 256) {
        int i = idx / 100, j = idx % 100;
        float s = 0.f;
#pragma unroll
        for (int d = 0; d < 32; ++d) s += qs[i * 32 + d] * ks2[j * 32 + d];
        lg2[i * 101 + j] = s * SCALE;
    }
    __syncthreads();
    if (tid < 100) {
        float m = -1e30f;
        for (int j = 0; j < 100; ++j) m = fmaxf(m, lg2[tid * 101 + j]);
        float s = 0.f;
        for (int j = 0; j < 100; ++j) {
            float e = __expf(lg2[tid * 101 + j] - m);
            lg2[tid * 101 + j] = e;
            s += e;
        }
        float inv = 1.0f / s;
        for (int j = 0; j < 100; ++j) lg2[tid * 101 + j] *= inv;
    }
    __syncthreads();
    for (int idx = tid; idx < 3200; idx += 256) {
        int i = idx >> 5, d = idx & 31;
        float s = 0.f;
        for (int j = 0; j < 100; ++j) s += lg2[i * 101 + j] * vs2[j * 32 + d];
        px_tok[(size_t)(rid0 + i) * 128 + 32 * h + d] = s;
    }
}

__global__ __launch_bounds__(256)
void tok_proj_kernel(const float* __restrict__ px_tok, const float* __restrict__ Wp,
                     const float* __restrict__ bp, float* __restrict__ out) {
    int gid = blockIdx.x * 256 + threadIdx.x;   // 0..102399
    int row = gid >> 7, c = gid & 127;
    int b = row / 200, rem = row % 200;
    const float* pr = px_tok + (size_t)row * 128;
    const float* wr = Wp + (size_t)c * 128;
    float s = 0.f;
#pragma unroll 8
    for (int k = 0; k < 128; ++k) s += pr[k] * wr[k];
    out[((size_t)b * TTOT + NPATCH + rem) * 128 + c] = s + bp[c];
}

// ---------------------------------------------------------------- launch
extern "C" void kernel_launch(void* const* d_in, const int* in_sizes, int n_in,
                              void* d_out, int out_size, void* d_ws, size_t ws_size,
                              hipStream_t stream) {
    const float* x         = (const float*)d_in[0];
    const float* det       = (const float*)d_in[1];
    const float* inter     = (const float*)d_in[2];
    const float* mask      = (const float*)d_in[3];
    const float* Wq        = (const float*)d_in[4];
    const float* bq        = (const float*)d_in[5];
    const float* Wp        = (const float*)d_in[6];
    const float* bp        = (const float*)d_in[7];
    const float* rel_table = (const float*)d_in[8];
    const int*   rel_index = (const int*)d_in[9];
    float* out = (float*)d_out;

    char* ws = (char*)d_ws;
    unsigned short* wq_b = (unsigned short*)(ws + WS_WQ);
    unsigned short* wp_b = (unsigned short*)(ws + WS_WP);
    float* biasT         = (float*)(ws + WS_BIAS);
    float* qkv_tok       = (float*)(ws + WS_QKVTOK);
    float* px_tok        = (float*)(ws + WS_QKVTOK + 800 * 384 * 4);  // reuse tail? no: separate
    // px_tok needs 800*128*4 = 409600 B; place after qkv_tok (196608+1228800=1425408)
    px_tok = (float*)(ws + 1425408);

    prep_kernel<<<320, 256, 0, stream>>>(Wq, Wp, rel_table, rel_index, wq_b, wp_b, biasT);
    tok_qkv_kernel<<<800, 256, 0, stream>>>(det, inter, Wq, bq, qkv_tok);
    tok_attn_kernel<<<32, 256, 0, stream>>>(qkv_tok, px_tok);
    tok_proj_kernel<<<400, 256, 0, stream>>>(px_tok, Wp, bp, out);
    win2_kernel<<<2048, 512, 0, stream>>>(x, mask, wq_b, bq, wp_b, bp, biasT, out);
}